// Round 4
// baseline (442.112 us; speedup 1.0000x reference)
//
#include <hip/hip_runtime.h>
#include <stdint.h>
#include <stddef.h>

#define NROWS 8192
#define DIM   1024
#define RB    512      // fp4 bytes per row (DIM/2)
#define TEMP  10.0f

#define BM 128         // A panel rows per block (64 KB LDS -> 2 blocks/CU)
#define BN 256         // B cols per output tile

typedef __attribute__((ext_vector_type(4))) int i32x4;
typedef __attribute__((ext_vector_type(8))) int i32x8;
typedef __attribute__((ext_vector_type(16))) float floatx16;

// async 16B global->LDS (global_load_lds_dwordx4); LDS dest is wave-uniform
// base + lane*16 -- all staging dests are slot*16 by construction.
__device__ __forceinline__ void load16_lds(const unsigned char* g, unsigned char* l) {
    __builtin_amdgcn_global_load_lds(
        (__attribute__((address_space(1))) void*)(g),
        (__attribute__((address_space(3))) void*)(l),
        16, 0, 0);
}

// fp4 e2m1 quantize of x (already in grid units, sigma~1): nearest of
// {0,.5,1,1.5,2,3,4,6} with sign. 7-threshold chain, branch-free.
__device__ __forceinline__ unsigned fp4q(float x) {
    float a = fabsf(x);
    a = fminf(a, 6.0f);
    unsigned c = (unsigned)(a >= 0.25f) + (unsigned)(a >= 0.75f)
               + (unsigned)(a >= 1.25f) + (unsigned)(a >= 1.75f)
               + (unsigned)(a >= 2.5f)  + (unsigned)(a >= 3.5f)
               + (unsigned)(a >= 5.0f);
    return c | ((__float_as_uint(x) >> 28) & 8u);
}

// fp4 operand: HW (cbsz=blgp=4) reads only regs 0..3; uppers UNDEF on purpose
// (no zero-movs, no pinned zero registers -- saves 4 VGPR per live tuple).
__device__ __forceinline__ i32x8 op8u(i32x4 lo) {
    return __builtin_shufflevector(lo, lo, 0, 1, 2, 3, -1, -1, -1, -1);
}

// ---------------------------------------------------------------------------
// Quantized layout (per matrix, 4 MB) -- MFMA-fragment-linear:
//   element e of row r: chunk c = e>>5 (16B = 32 fp4), it = c>>2,
//   ks = (c>>1)&1, fh = c&1
//   byte = it*524288 + (r>>5)*2048 + ks*1024 + fh*512 + (r&31)*16
// => per (rowgroup, it, ks): 1 KB fragment, lane-linear (lane = fh*32 + fr,
//    16 B per lane). Fragment reads need ZERO address swizzle: LDS frags are
//    ds_read_b128 at base+lane*16+imm (conflict-free), B frags are
//    global_load_dwordx4 of a contiguous 1 KB per wave (coalesced).
//    A 128-row panel within one it-slab is 8 KB CONTIGUOUS.
// ---------------------------------------------------------------------------

// Wave-per-row L2 normalize + quantize to fp4 e2m1 at fixed scale 2^-5
// (values x32 -> sigma ~1 grid unit). Fragment-linear stores via small LDS
// transpose bounce.
__global__ __launch_bounds__(256) void normalize_kernel(
    const float* __restrict__ img, const float* __restrict__ txt,
    unsigned char* __restrict__ imgq, unsigned char* __restrict__ txtq,
    float* __restrict__ out)
{
    __shared__ __align__(16) unsigned short sc[4][256];   // [wave][c*64+lane]
    const int t = threadIdx.x;
    const int lane = t & 63, wave = t >> 6;
    const int gw = blockIdx.x * 4 + wave;                 // row id, 0..16383
    const float* src = (gw < NROWS) ? img + (size_t)gw * DIM
                                    : txt + (size_t)(gw - NROWS) * DIM;
    float4 v[4];
    float ss = 0.f;
#pragma unroll
    for (int c = 0; c < 4; c++) {
        v[c] = ((const float4*)src)[lane + 64 * c];
        ss += v[c].x * v[c].x + v[c].y * v[c].y + v[c].z * v[c].z + v[c].w * v[c].w;
    }
#pragma unroll
    for (int off = 32; off; off >>= 1) ss += __shfl_xor(ss, off);
    const float scale = 32.0f / fmaxf(sqrtf(ss), 1e-12f);   // x32 = fp4 grid
#pragma unroll
    for (int c = 0; c < 4; c++) {
        unsigned p = fp4q(v[c].x * scale)
                   | (fp4q(v[c].y * scale) << 4)
                   | (fp4q(v[c].z * scale) << 8)
                   | (fp4q(v[c].w * scale) << 12);
        sc[wave][c * 64 + lane] = (unsigned short)p;   // ushort u covers elems [4u,4u+4)
    }
    __syncthreads();
    // 128 store units: (rr = row in block 0..3, k = chunk 0..31). Chunk k =
    // ushorts [8k..8k+8) of row rr. 4 consecutive t share (it,ks,fh) and write
    // 4 consecutive fr*16 slots -> 64B-line coalesced.
    if (t < 128) {
        const int rr = t & 3, k = t >> 2;
        const int gr0 = blockIdx.x * 4;      // block never straddles img/txt (4 | 8192)
        unsigned char* dq = (gr0 < NROWS) ? imgq : txtq;
        const int r = (gr0 < NROWS ? gr0 : gr0 - NROWS) + rr;
        const int4 d = *(const int4*)&sc[rr][k * 8];
        const int it = k >> 2, ks = (k >> 1) & 1, fh = k & 1;
        *(int4*)(dq + (size_t)it * 524288 + (size_t)((r >> 5) * 2048
                 + ks * 1024 + fh * 512 + (r & 31) * 16)) = d;
    }
    if (gw == 0 && lane == 0) out[0] = 0.f;   // zero the atomic target
}

// NT-GEMM on fp4 e2m1 via MX-scaled MFMA 32x32x64, occupancy-first:
// 512 blocks x 512 threads (8 waves), 2 blocks/CU (64 KB LDS each) ->
// 4 waves/SIMD. Wave tile 64x64 (acc = 64 VGPR); with B double-buffer and
// undef-upper operands the live set fits the 128-reg cap of
// __launch_bounds__(512,4) WITHOUT spill.
// Each block: A panel (128 rows) RESIDENT in LDS, loaded once, read-only,
// lane-linear conflict-free; sweeps 4 output tiles n = n0+8k. B operands
// fetched straight from L2 into regs (n0 = bid&7 matches the XCD round-robin
// -> each XCD's L2 holds one 512 KB B strip). ZERO barriers in the main
// stream; 16 drifting waves/CU hide MFMA latency, L2 latency, and each
// other's epilogues. Two independent blocks/CU overlap epilogue with GEMM.
__global__ __launch_bounds__(512, 4) void simloss_kernel(
    const unsigned char* __restrict__ An,   // img fp4, fragment-linear
    const unsigned char* __restrict__ Bn,   // txt fp4, fragment-linear
    const float* __restrict__ bias,
    float* __restrict__ out)
{
    __shared__ __align__(16) unsigned char As[8 * 8192];   // resident A panel

    const int t = threadIdx.x;
    const int lane = t & 63;
    const int wave = t >> 6;

    const int bid = blockIdx.x;        // 0..511
    const int blockM = bid >> 3;       // 0..63, fixed per block
    const int n0 = bid & 7;            // XCD-correlated N start

    // ---- prologue: DMA the whole A panel into LDS (8 x 8 KB slabs) ----
    {
        const unsigned char* gA = An + (size_t)blockM * 8192 + t * 16;
#pragma unroll
        for (int it = 0; it < 8; it++)
            load16_lds(gA + (size_t)it * 524288, As + it * 8192 + t * 16);
    }
    asm volatile("s_waitcnt vmcnt(0)" ::: "memory");
    __syncthreads();                   // the ONLY structural barrier

    // wave grid 2(M) x 4(N); wave tile 64x64 = 2x2 MFMA tiles
    const int rgA = (wave >> 2) * 2;    // A rowgroup base (of 4)
    const int cgB = (wave & 3) * 2;     // B rowgroup base (of 8)
    const int fr = lane & 31;
    const int fh = lane >> 5;
    const int vA0 = rgA * 2048 + lane * 16;   // LDS byte offset base

    const float bv = bias[0];
    const float c1 = -TEMP * 1.4426950408889634f / 1024.0f;  // on raw acc
    const float c0 = bv * 1.4426950408889634f;

    for (int k = 0; k < 4; ++k) {               // runtime loop (small I$)
        const int n = n0 + 8 * k;
        const unsigned char* gB = Bn + (size_t)((n * 8 + cgB) * 2048 + lane * 16);

        floatx16 acc[2][2];
#pragma unroll
        for (int mi = 0; mi < 2; mi++)
#pragma unroll
            for (int ni = 0; ni < 2; ni++)
                acc[mi][ni] = (floatx16)(0.f);

        // B frag sets (dbuf): [ks*2+ni] at ni*2048 + ks*1024 within it-slab
        i32x4 b0[4], b1[4];
#pragma unroll
        for (int j = 0; j < 4; j++)
            b0[j] = *(const i32x4*)(gB + (j >> 1) * 1024 + (j & 1) * 2048);

        int vA = vA0;
        for (int pp = 0; pp < 4; ++pp) {        // 2 its per iteration
            // ---- it = 2pp: compute from b0, prefetch it 2pp+1 -> b1 ----
            {
                i32x4 a[2][2];                  // [ks][mi]
#pragma unroll
                for (int ks = 0; ks < 2; ks++)
#pragma unroll
                    for (int mi = 0; mi < 2; mi++)
                        a[ks][mi] = *(const i32x4*)&As[vA + mi * 2048 + ks * 1024];
                const unsigned char* gB1 = gB + 524288;
#pragma unroll
                for (int j = 0; j < 4; j++)
                    b1[j] = *(const i32x4*)(gB1 + (j >> 1) * 1024 + (j & 1) * 2048);
#pragma unroll
                for (int ks = 0; ks < 2; ks++)
#pragma unroll
                    for (int mi = 0; mi < 2; mi++)
#pragma unroll
                        for (int ni = 0; ni < 2; ni++)
                            acc[mi][ni] = __builtin_amdgcn_mfma_scale_f32_32x32x64_f8f6f4(
                                op8u(a[ks][mi]), op8u(b0[ks * 2 + ni]), acc[mi][ni],
                                4, 4,                 // cbsz=blgp=FP4(e2m1)
                                0, 0x7f7f7f7f,        // scale_a = 2^0
                                0, 0x7f7f7f7f);       // scale_b = 2^0
            }
            vA += 8192;
            gB += 2 * 524288;                   // now points at it 2pp+2
            // ---- it = 2pp+1: compute from b1, prefetch it 2pp+2 -> b0 ----
            {
                i32x4 a[2][2];
#pragma unroll
                for (int ks = 0; ks < 2; ks++)
#pragma unroll
                    for (int mi = 0; mi < 2; mi++)
                        a[ks][mi] = *(const i32x4*)&As[vA + mi * 2048 + ks * 1024];
                if (pp < 3) {
#pragma unroll
                    for (int j = 0; j < 4; j++)
                        b0[j] = *(const i32x4*)(gB + (j >> 1) * 1024 + (j & 1) * 2048);
                }
#pragma unroll
                for (int ks = 0; ks < 2; ks++)
#pragma unroll
                    for (int mi = 0; mi < 2; mi++)
#pragma unroll
                        for (int ni = 0; ni < 2; ni++)
                            acc[mi][ni] = __builtin_amdgcn_mfma_scale_f32_32x32x64_f8f6f4(
                                op8u(a[ks][mi]), op8u(b1[ks * 2 + ni]), acc[mi][ni],
                                4, 4,
                                0, 0x7f7f7f7f,
                                0, 0x7f7f7f7f);
            }
            vA += 8192;
        }

        // ---- epilogue for tile (blockM rows, n cols). Raw acc = 1024*sim.
        // logit = -10*sim + b, x = label*logit;
        //   softplus(x) = (x+|x|)/2 + log(1+e^-|x|);
        //   sum(x)/2 = sum_diag(logit) - sum_all(logit)/2   (linear!)
        // log2 domain, PRODUCT trick: one v_log per 8 logits:
        //   sum log2(1+2^-|w|) = log2( prod (1+2^-|w_i|) ), prod in (1,256].
        float accP = 0.f, accQ = 0.f, accD = 0.f;
#pragma unroll
        for (int mi = 0; mi < 2; mi++) {
#pragma unroll
            for (int ni = 0; ni < 2; ni++) {
#pragma unroll
                for (int g = 0; g < 2; g++) {
                    float prod = 1.0f;
#pragma unroll
                    for (int r8 = 0; r8 < 8; r8++) {
                        float sv = acc[mi][ni][g * 8 + r8];   // raw = 1024*sim
                        float w = fmaf(sv, c1, c0);
                        float aw = fabsf(w);
                        prod *= 1.0f + __builtin_amdgcn_exp2f(-aw);
                        accP = fmaf(0.5f, aw, accP);
                        accQ += sv;
                    }
                    accP += __builtin_amdgcn_logf(prod);      // v_log = log2
                }
            }
        }
        // diag elements exist iff A rows [blockM*128,+128) meet B cols
        // [n*256,+256): n == blockM>>1. 128 diag elems in such a block.
        const bool diagblk = (n == (blockM >> 1));
        if (diagblk) {
            const int gi0 = blockM * BM + (wave >> 2) * 64 + 4 * fh;
            const int gj0 = n * BN + (wave & 3) * 64 + fr;
#pragma unroll
            for (int mi = 0; mi < 2; mi++)
#pragma unroll
                for (int ni = 0; ni < 2; ni++)
#pragma unroll
                    for (int reg = 0; reg < 16; reg++) {
                        int ig = gi0 + mi * 32 + (reg & 3) + 8 * (reg >> 2);
                        int jg = gj0 + ni * 32;
                        if (ig == jg) accD += acc[mi][ni][reg];
                    }
        }
#pragma unroll
        for (int off = 32; off; off >>= 1) {
            accP += __shfl_xor(accP, off);
            accQ += __shfl_xor(accQ, off);
            accD += __shfl_xor(accD, off);
        }
        // per-wave contribution (all linear):
        //   ln2*P + 5*(Qraw/1024) - 10*(Draw/1024); block consts via wave 0:
        //   -(Ne/2)*b = -16384*b, diag adds Nd*b = 128*b.
        if (lane == 0) {
            float wcon = fmaf(0.6931471805599453f, accP,
                              fmaf(5.0f / 1024.0f, accQ,
                                   diagblk ? (-TEMP / 1024.0f) * accD : 0.f));
            if (wave == 0)
                wcon += fmaf(-16384.0f, bv, diagblk ? 128.0f * bv : 0.f);
            atomicAdd(out, wcon * (1.0f / 8192.0f));
        }
    }
}

extern "C" void kernel_launch(void* const* d_in, const int* in_sizes, int n_in,
                              void* d_out, int out_size, void* d_ws, size_t ws_size,
                              hipStream_t stream) {
    const float* txt = (const float*)d_in[0];   // text_embeddings [8192][1024]
    const float* img = (const float*)d_in[1];   // image_embeddings [8192][1024]
    const float* bias = (const float*)d_in[2];  // [1]
    float* out = (float*)d_out;

    unsigned char* imgq = (unsigned char*)d_ws;                      // 4 MB fp4
    unsigned char* txtq = imgq + (size_t)NROWS * RB;                 // 4 MB fp4

    normalize_kernel<<<dim3(2 * NROWS / 4), dim3(256), 0, stream>>>(
        img, txt, imgq, txtq, out);

    simloss_kernel<<<dim3((NROWS / BM) * 8), dim3(512), 0, stream>>>(
        imgq, txtq, bias, out);
}

// Round 7
// 142.985 us; speedup vs baseline: 3.0920x; 3.0920x over previous
//
#include <hip/hip_runtime.h>
#include <stdint.h>
#include <stddef.h>

#define NROWS 8192
#define DIM   1024
#define RB    512      // fp4 bytes per row (DIM/2)
#define TEMP  10.0f

#define BM 128         // A panel rows per block (64 KB LDS -> 2 blocks/CU)
#define BN 128         // B cols per n-tile

typedef __attribute__((ext_vector_type(4))) int i32x4;
typedef __attribute__((ext_vector_type(8))) int i32x8;
typedef __attribute__((ext_vector_type(16))) float floatx16;

// async 16B global->LDS (global_load_lds_dwordx4); LDS dest is wave-uniform
// base + lane*16 -- all staging dests are slot*16 by construction.
__device__ __forceinline__ void load16_lds(const unsigned char* g, unsigned char* l) {
    __builtin_amdgcn_global_load_lds(
        (__attribute__((address_space(1))) void*)(g),
        (__attribute__((address_space(3))) void*)(l),
        16, 0, 0);
}

// fp4 e2m1 quantize of x (already in grid units, sigma~1): nearest of
// {0,.5,1,1.5,2,3,4,6} with sign. 7-threshold chain, branch-free.
__device__ __forceinline__ unsigned fp4q(float x) {
    float a = fabsf(x);
    a = fminf(a, 6.0f);
    unsigned c = (unsigned)(a >= 0.25f) + (unsigned)(a >= 0.75f)
               + (unsigned)(a >= 1.25f) + (unsigned)(a >= 1.75f)
               + (unsigned)(a >= 2.5f)  + (unsigned)(a >= 3.5f)
               + (unsigned)(a >= 5.0f);
    return c | ((__float_as_uint(x) >> 28) & 8u);
}

// fp4 operand: HW (cbsz=blgp=4) reads only regs 0..3; uppers UNDEF on purpose
// (no zero-movs, no pinned zero registers). Ran verified in r4.
__device__ __forceinline__ i32x8 op8u(i32x4 lo) {
    return __builtin_shufflevector(lo, lo, 0, 1, 2, 3, -1, -1, -1, -1);
}

// ---------------------------------------------------------------------------
// Quantized layout (per matrix, 4 MB) -- MFMA-fragment-linear:
//   element e of row r: chunk c = e>>5 (16B = 32 fp4), it = c>>2,
//   ks = (c>>1)&1, fh = c&1
//   byte = it*524288 + (r>>5)*2048 + ks*1024 + fh*512 + (r&31)*16
// => per (rowgroup, it, ks): 1 KB fragment, lane-linear (lane = fh*32 + fr,
//    16 B per lane). Fragment reads need ZERO address swizzle: LDS frags are
//    ds_read_b128 at base+lane*16+imm (conflict-free), B frags are
//    global_load_dwordx4 at one base + small imm (coalesced 1 KB/wave).
//    A 128-row panel within one it-slab is 8 KB CONTIGUOUS.
// ---------------------------------------------------------------------------

// Wave-per-row L2 normalize + quantize to fp4 e2m1 at fixed scale 2^-5
// (values x32 -> sigma ~1 grid unit). Fragment-linear stores via small LDS
// transpose bounce. (Unchanged since r1; passes.)
__global__ __launch_bounds__(256) void normalize_kernel(
    const float* __restrict__ img, const float* __restrict__ txt,
    unsigned char* __restrict__ imgq, unsigned char* __restrict__ txtq,
    float* __restrict__ out)
{
    __shared__ __align__(16) unsigned short sc[4][256];   // [wave][c*64+lane]
    const int t = threadIdx.x;
    const int lane = t & 63, wave = t >> 6;
    const int gw = blockIdx.x * 4 + wave;                 // row id, 0..16383
    const float* src = (gw < NROWS) ? img + (size_t)gw * DIM
                                    : txt + (size_t)(gw - NROWS) * DIM;
    float4 v[4];
    float ss = 0.f;
#pragma unroll
    for (int c = 0; c < 4; c++) {
        v[c] = ((const float4*)src)[lane + 64 * c];
        ss += v[c].x * v[c].x + v[c].y * v[c].y + v[c].z * v[c].z + v[c].w * v[c].w;
    }
#pragma unroll
    for (int off = 32; off; off >>= 1) ss += __shfl_xor(ss, off);
    const float scale = 32.0f / fmaxf(sqrtf(ss), 1e-12f);   // x32 = fp4 grid
#pragma unroll
    for (int c = 0; c < 4; c++) {
        unsigned p = fp4q(v[c].x * scale)
                   | (fp4q(v[c].y * scale) << 4)
                   | (fp4q(v[c].z * scale) << 8)
                   | (fp4q(v[c].w * scale) << 12);
        sc[wave][c * 64 + lane] = (unsigned short)p;   // ushort u covers elems [4u,4u+4)
    }
    __syncthreads();
    // 128 store units: (rr = row in block 0..3, k = chunk 0..31). Chunk k =
    // ushorts [8k..8k+8) of row rr. 4 consecutive t share (it,ks,fh) and write
    // 4 consecutive fr*16 slots -> 64B-line coalesced.
    if (t < 128) {
        const int rr = t & 3, k = t >> 2;
        const int gr0 = blockIdx.x * 4;      // block never straddles img/txt (4 | 8192)
        unsigned char* dq = (gr0 < NROWS) ? imgq : txtq;
        const int r = (gr0 < NROWS ? gr0 : gr0 - NROWS) + rr;
        const int4 d = *(const int4*)&sc[rr][k * 8];
        const int it = k >> 2, ks = (k >> 1) & 1, fh = k & 1;
        *(int4*)(dq + (size_t)it * 524288 + (size_t)((r >> 5) * 2048
                 + ks * 1024 + fh * 512 + (r & 31) * 16)) = d;
    }
    if (gw == 0 && lane == 0) out[0] = 0.f;   // zero the atomic target
}

// NT-GEMM on fp4 e2m1 via MX-scaled MFMA 32x32x64, occupancy-first, with a
// register plan that FITS the (512,4) unified 128-reg cap (r4 lesson: the
// cap covers VGPR+AGPR combined; acc must be 32, not 64):
//   acc[2] (32 AGPR) + aE/aO (16) + bE/bO (32) + addr/scalars (~30) ~= 110.
// 512 blocks x 512 threads (8 waves), 64 KB LDS -> 2 blocks/CU -> 4
// waves/SIMD. Each block: A panel (128 rows) resident in LDS (loaded once,
// read-only, lane-linear conflict-free); sweeps 8 n-tiles of 128 cols in its
// n0 strip (n0 = bid&7 matches XCD round-robin; per-XCD B strip = 512 KB,
// L2-hot). Wave grid 4(M)x2(N): wave tile 32x64; B reg-direct from L2.
// Depth-1 even/odd prefetch; per step (one it): 2 ds_read_b128 +
// 4 global_load_dwordx4 + 4 MFMA. Zero barriers in the main stream; 16
// drifting waves/CU (2 independent blocks) hide MFMA latency, L2 latency,
// and each other's epilogues.
__global__ __launch_bounds__(512, 4) void simloss_kernel(
    const unsigned char* __restrict__ An,   // img fp4, fragment-linear
    const unsigned char* __restrict__ Bn,   // txt fp4, fragment-linear
    const float* __restrict__ bias,
    float* __restrict__ out)
{
    __shared__ __align__(16) unsigned char As[8 * 8192];   // 64 KB A panel
    __shared__ float red[3][8];

    const int t = threadIdx.x;
    const int lane = t & 63;
    const int wave = t >> 6;            // 0..7

    const int bid = blockIdx.x;         // 0..511
    const int blockM = bid >> 3;        // 0..63
    const int n0 = bid & 7;             // XCD-correlated N strip

    // ---- prologue: DMA the A panel into LDS (8 x 8 KB slabs) ----
    {
        const unsigned char* gA = An + (size_t)blockM * 8192 + t * 16;
#pragma unroll
        for (int it = 0; it < 8; it++)
            load16_lds(gA + (size_t)it * 524288, As + it * 8192 + t * 16);
    }
    asm volatile("s_waitcnt vmcnt(0)" ::: "memory");
    __syncthreads();                    // the only pre-epilogue barrier

    // wave grid 4(M) x 2(N): rows = rgHalf*32, cols = nHalf*64 within tile
    const int rgHalf = wave >> 1;       // 0..3 (A rowgroup)
    const int nHalf = wave & 1;         // 0..1
    const int fr = lane & 31;
    const int fh = lane >> 5;
    const int vA0 = rgHalf * 2048 + lane * 16;   // LDS fragment base

    const float bv = bias[0];
    const float c1 = -TEMP * 1.4426950408889634f / 1024.0f;  // on raw acc
    const float c0 = bv * 1.4426950408889634f;

    // diag: rows [blockM*128,+128) meet cols [n*128,+128) iff n == blockM,
    // i.e. (blockM&7)==n0 at j = blockM>>3 (then n = blockM exactly).
    const bool diagAny = (blockM & 7) == n0;
    const int jd = blockM >> 3;

    float accP = 0.f, accQ = 0.f, accD = 0.f;

    for (int j = 0; j < 8; ++j) {       // runtime n-tile loop (small I$)
        const int n = n0 + 8 * j;       // cols [n*128, +128)
        const unsigned char* gB = Bn
            + (size_t)((n * 4 + nHalf * 2) * 2048 + lane * 16);

        floatx16 acc[2];
        acc[0] = (floatx16)(0.f);
        acc[1] = (floatx16)(0.f);

        // depth-1 even/odd pipeline over it = 0..7 (static sets, rule #20)
        i32x4 aE[2], aO[2], bE[4], bO[4];
        // preload it=0 into the even set
#pragma unroll
        for (int ks = 0; ks < 2; ks++)
            aE[ks] = *(const i32x4*)&As[vA0 + ks * 1024];
#pragma unroll
        for (int q = 0; q < 4; q++)
            bE[q] = *(const i32x4*)(gB + (q & 1) * 2048 + (q >> 1) * 1024);

#pragma unroll
        for (int pp = 0; pp < 4; ++pp) {
            // load odd set (it = 2pp+1)
#pragma unroll
            for (int ks = 0; ks < 2; ks++)
                aO[ks] = *(const i32x4*)&As[vA0 + (2 * pp + 1) * 8192 + ks * 1024];
#pragma unroll
            for (int q = 0; q < 4; q++)
                bO[q] = *(const i32x4*)(gB + (size_t)(2 * pp + 1) * 524288
                                        + (q & 1) * 2048 + (q >> 1) * 1024);
            // compute even set (it = 2pp)
#pragma unroll
            for (int ks = 0; ks < 2; ks++)
#pragma unroll
                for (int ni = 0; ni < 2; ni++)
                    acc[ni] = __builtin_amdgcn_mfma_scale_f32_32x32x64_f8f6f4(
                        op8u(aE[ks]), op8u(bE[ks * 2 + ni]), acc[ni],
                        4, 4,                 // cbsz=blgp=FP4(e2m1)
                        0, 0x7f7f7f7f,        // scale_a = 2^0
                        0, 0x7f7f7f7f);       // scale_b = 2^0
            // load even set (it = 2pp+2)
            if (pp < 3) {
#pragma unroll
                for (int ks = 0; ks < 2; ks++)
                    aE[ks] = *(const i32x4*)&As[vA0 + (2 * pp + 2) * 8192 + ks * 1024];
#pragma unroll
                for (int q = 0; q < 4; q++)
                    bE[q] = *(const i32x4*)(gB + (size_t)(2 * pp + 2) * 524288
                                            + (q & 1) * 2048 + (q >> 1) * 1024);
            }
            // compute odd set (it = 2pp+1)
#pragma unroll
            for (int ks = 0; ks < 2; ks++)
#pragma unroll
                for (int ni = 0; ni < 2; ni++)
                    acc[ni] = __builtin_amdgcn_mfma_scale_f32_32x32x64_f8f6f4(
                        op8u(aO[ks]), op8u(bO[ks * 2 + ni]), acc[ni],
                        4, 4,
                        0, 0x7f7f7f7f,
                        0, 0x7f7f7f7f);
        }

        // ---- epilogue for this 32x64 wave tile. Raw acc = 1024*sim. ----
        // logit = -10*sim + b, x = label*logit;
        //   softplus(x) = (x+|x|)/2 + log(1+e^-|x|);
        //   sum(x)/2 = sum_diag(logit) - sum_all(logit)/2   (linear!)
        // log2 domain, PRODUCT trick: one v_log per 8 logits:
        //   sum log2(1+2^-|w|) = log2( prod (1+2^-|w_i|) ), prod in (1,256].
#pragma unroll
        for (int ni = 0; ni < 2; ni++) {
#pragma unroll
            for (int g = 0; g < 2; g++) {
                float prod = 1.0f;
#pragma unroll
                for (int r8 = 0; r8 < 8; r8++) {
                    float sv = acc[ni][g * 8 + r8];       // raw = 1024*sim
                    float w = fmaf(sv, c1, c0);
                    float aw = fabsf(w);
                    prod *= 1.0f + __builtin_amdgcn_exp2f(-aw);
                    accP = fmaf(0.5f, aw, accP);
                    accQ += sv;
                }
                accP += __builtin_amdgcn_logf(prod);      // v_log = log2
            }
        }
        if (diagAny && j == jd) {       // n == blockM here
            const int gi0 = blockM * BM + rgHalf * 32 + 4 * fh;
            const int gj0 = n * BN + nHalf * 64 + fr;
#pragma unroll
            for (int ni = 0; ni < 2; ni++)
#pragma unroll
                for (int reg = 0; reg < 16; reg++) {
                    int ig = gi0 + (reg & 3) + 8 * (reg >> 2);
                    int jg = gj0 + ni * 32;
                    if (ig == jg) accD += acc[ni][reg];
                }
        }
    }

    // ---- block reduction: 1 atomic per block (512 total) ----
#pragma unroll
    for (int off = 32; off; off >>= 1) {
        accP += __shfl_xor(accP, off);
        accQ += __shfl_xor(accQ, off);
        accD += __shfl_xor(accD, off);
    }
    if (lane == 0) {
        red[0][wave] = accP;
        red[1][wave] = accQ;
        red[2][wave] = accD;
    }
    __syncthreads();
    if (t == 0) {
        float P = 0.f, Q = 0.f, D = 0.f;
#pragma unroll
        for (int w = 0; w < 8; w++) {
            P += red[0][w];
            Q += red[1][w];
            D += red[2][w];
        }
        // ln2*P + 5*(Qraw/1024) - 10*(Draw/1024) + bias consts:
        // block covers 128x1024 elems -> -(Ne/2)*b = -65536*b;
        // diag block adds Nd*b = 128*b.
        float contrib = fmaf(0.6931471805599453f, P,
                             fmaf(5.0f / 1024.0f, Q, (-TEMP / 1024.0f) * D));
        contrib += fmaf(-65536.0f, bv, diagAny ? 128.0f * bv : 0.f);
        atomicAdd(out, contrib * (1.0f / 8192.0f));
    }
}

extern "C" void kernel_launch(void* const* d_in, const int* in_sizes, int n_in,
                              void* d_out, int out_size, void* d_ws, size_t ws_size,
                              hipStream_t stream) {
    const float* txt = (const float*)d_in[0];   // text_embeddings [8192][1024]
    const float* img = (const float*)d_in[1];   // image_embeddings [8192][1024]
    const float* bias = (const float*)d_in[2];  // [1]
    float* out = (float*)d_out;

    unsigned char* imgq = (unsigned char*)d_ws;                      // 4 MB fp4
    unsigned char* txtq = imgq + (size_t)NROWS * RB;                 // 4 MB fp4

    normalize_kernel<<<dim3(2 * NROWS / 4), dim3(256), 0, stream>>>(
        img, txt, imgq, txtq, out);

    simloss_kernel<<<dim3((NROWS / BM) * 8), dim3(512), 0, stream>>>(
        imgq, txtq, bias, out);
}